// Round 8
// baseline (208.048 us; speedup 1.0000x reference)
//
#include <hip/hip_runtime.h>
#include <math.h>

// DoG seasonal: out[b,l,c] = (k1*x)(l) - (k2*x)(l), depthwise over c, reflect pad.
// k1: sigma=4.2 (35 taps) exact. k2: sigma=96 (769 taps) via Gaussian pyramid:
//   A: d = (G12 * x) decimated by 16 (97 taps); B: e = gb * d (49 taps);
//   C (narrow): exact 35-tap conv + linear interp of e + subtract.
// R2: gather-form only (scatter -> scratch). R4: never cap VGPR below footprint.
// R5/R6: VALU not the wall (pk_fma halved VALU, dur unchanged).
// R7: intra-block pipelining null too. Invariant across r1-r7: 256B-chunk
//   strided reads/writes -> ~1.8 TB/s effective write BW (fill kernel: 6.9).
// R8 (this): full-row blocks. Stage = contiguous 64KB global_load_lds (dbuf),
//   compute = f32x2 column-pair gather, store = contiguous 20.5KB float4 burst.

#define Bdim 32
#define Ldim 4096
#define Cdim 321

#define R1 17
#define K1n 35
#define R2 384
#define K2n 769

#define GA_R 48
#define GA_N 97          // sigma_a = 12
#define GB_R 24
#define GB_N 49          // sigma_b = sqrt(96^2-12^2)/16 on coarse grid

#define NG 257           // e grid: j = 0..256 at l = 16j
#define NJD 305          // d grid: jj = -24..280 stored at jj+24
#define NGRP_A 20        // stage A: groups of 16 d-points
#define NTJ 33           // stage B: groups of 8 outputs

// narrow dense-row tiling
#define TLD 16           // l per iteration
#define TRWD 50          // TLD + 2*R1
#define XTF 16384        // floats staged per buffer (4096 x4-chunks, >= 50*321)
#define NITER 8          // iters per block
#define LBLK 128         // l per block
#define NLG 32           // Ldim / LBLK
#define OBF (TLD*Cdim)   // 5136 floats out-tile
#define NSEG 128         // reg-form fallback: segments of 32 outputs

// workspace float offsets
#define GA_OFF 0
#define GB_OFF 128
#define W1_OFF 192
#define K2_OFF 256       // 769 linear taps (naive fallback)
#define K2P_OFF 1088     // 784 polyphase-padded taps (middle fallback)
#define E2_OFF 4096      // middle-path e grid
#define D_OFF 4096       // pyramid d grid
#define E_OFF (D_OFF + Bdim*NJD*Cdim)            // 4096 + 3,132,960
#define WS_TOT (E_OFF + Bdim*NG*Cdim)            // + 2,639,904 floats

typedef float f32x2 __attribute__((ext_vector_type(2)));

__device__ __forceinline__ int mirror_idx(int a) {
    a = a < 0 ? -a : a;
    a = a > (Ldim - 1) ? 2 * (Ldim - 1) - a : a;
    return a;
}

__device__ __forceinline__ int xcd_swizzle(int bid, int nwg) {
    // bijective XCD-chunk remap (m204)
    int q = nwg >> 3, r = nwg & 7;
    int xcd = bid & 7, i = bid >> 3;
    int base = (xcd < r) ? xcd * (q + 1) : r * (q + 1) + (xcd - r) * q;
    return base + i;
}

__device__ __forceinline__ float block_sum_1024(float v, float* partial) {
#pragma unroll
    for (int off = 32; off >= 1; off >>= 1) v += __shfl_down(v, off, 64);
    __syncthreads();
    if ((threadIdx.x & 63) == 0) partial[threadIdx.x >> 6] = v;
    __syncthreads();
    float s = partial[0];
#pragma unroll
    for (int i = 1; i < 16; ++i) s += partial[i];
    return s;
}

__global__ void init_weights_kernel(float* __restrict__ w) {
    __shared__ float partial[16];
    const int tid = threadIdx.x;  // 1024 threads

    {   // ga: sigma 12, radius 48
        float v = 0.f;
        if (tid < GA_N) { float t = (float)(tid - GA_R) * (1.0f / 12.0f); v = expf(-0.5f * t * t); }
        float s = block_sum_1024(v, partial);
        if (tid < GA_N) w[GA_OFF + tid] = v / s;
    }
    {   // gb
        const float sb = sqrtf(96.f * 96.f - 12.f * 12.f) * (1.0f / 16.0f);
        float v = 0.f;
        if (tid < GB_N) { float t = (float)(tid - GB_R) / sb; v = expf(-0.5f * t * t); }
        float s = block_sum_1024(v, partial);
        if (tid < GB_N) w[GB_OFF + tid] = v / s;
    }
    {   // w1: sigma 4.2
        float v = 0.f;
        if (tid < K1n) { float t = (float)(tid - R1) * (1.0f / 4.2f); v = expf(-0.5f * t * t); }
        float s = block_sum_1024(v, partial);
        if (tid < K1n) w[W1_OFF + tid] = v / s;
    }
    {   // k2: sigma 96 (fallbacks)
        float v = 0.f;
        if (tid < K2n) { float t = (float)(tid - R2) * (1.0f / 96.0f); v = expf(-0.5f * t * t); }
        float s = block_sum_1024(v, partial);
        if (tid < K2n) w[K2_OFF + tid] = v / s;
        if (tid < 784) w[K2P_OFF + tid] = (tid < K2n) ? v / s : 0.f;
    }
}

// ---- Stage A: d[b, jj+24, c], polyphase decimate-by-16 with G12 (97 taps)
__global__ __launch_bounds__(256) void decimA_kernel(
        const float* __restrict__ x, const float* __restrict__ ga,
        float* __restrict__ d) {
    __shared__ float gs[GA_N];
    if (threadIdx.x < GA_N) gs[threadIdx.x] = ga[threadIdx.x];
    __syncthreads();

    const int lb = xcd_swizzle(blockIdx.x, gridDim.x);
    const int lin = lb * 256 + threadIdx.x;
    const int c = lin % Cdim;
    const int rest = lin / Cdim;
    const int g = rest % NGRP_A;
    const int b = rest / NGRP_A;
    if (b >= Bdim) return;

    const int jj0 = -24 + 16 * g;
    const float* xb = x + b * (Ldim * Cdim) + c;

    float acc[16];
#pragma unroll
    for (int ii = 0; ii < 16; ++ii) acc[ii] = 0.f;

    const bool interior = (jj0 >= 3) && (jj0 <= 237);

#pragma unroll 1
    for (int p = 0; p < 16; ++p) {
        float row[22];
        if (interior) {
            const float* xp = xb + (16 * (jj0 - 3) + p) * Cdim;
#pragma unroll
            for (int i = 0; i < 22; ++i) row[i] = xp[i * (16 * Cdim)];
        } else {
#pragma unroll
            for (int i = 0; i < 22; ++i)
                row[i] = xb[mirror_idx(16 * (jj0 - 3 + i) + p) * Cdim];
        }
#pragma unroll
        for (int q = 0; q < 6; ++q) {
            const float wq = gs[16 * q + p];
#pragma unroll
            for (int ii = 0; ii < 16; ++ii)
                acc[ii] = fmaf(wq, row[ii + q], acc[ii]);
        }
        if (p == 0) {
            const float w6 = gs[96];
#pragma unroll
            for (int ii = 0; ii < 16; ++ii)
                acc[ii] = fmaf(w6, row[ii + 6], acc[ii]);
        }
    }

    const int j0d = jj0 + 24;
    float* db = d + (b * NJD + j0d) * Cdim + c;
#pragma unroll
    for (int ii = 0; ii < 16; ++ii)
        if (j0d + ii < NJD) db[ii * Cdim] = acc[ii];
}

// ---- Stage B: e = gb * d on coarse grid
__global__ __launch_bounds__(256) void coarseB_kernel(
        const float* __restrict__ d, const float* __restrict__ gb,
        float* __restrict__ e) {
    __shared__ float gbs[GB_N];
    if (threadIdx.x < GB_N) gbs[threadIdx.x] = gb[threadIdx.x];
    __syncthreads();

    const int lin = blockIdx.x * 256 + threadIdx.x;
    const int c = lin % Cdim;
    const int rest = lin / Cdim;
    const int tj = rest % NTJ;
    const int b = rest / NTJ;
    if (b >= Bdim) return;

    const int j0 = tj * 8;
    const float* db = d + b * (NJD * Cdim) + c;

    float row[56];
#pragma unroll
    for (int r = 0; r < 56; ++r) {
        int idx = j0 + r;
        idx = idx > (NJD - 1) ? (NJD - 1) : idx;
        row[r] = db[idx * Cdim];
    }

    float acc[8];
#pragma unroll
    for (int jj = 0; jj < 8; ++jj) acc[jj] = 0.f;
#pragma unroll
    for (int s = 0; s < GB_N; ++s) {
        const float wv = gbs[s];
#pragma unroll
        for (int jj = 0; jj < 8; ++jj)
            acc[jj] = fmaf(wv, row[s + jj], acc[jj]);
    }

    float* eb = e + (b * NG + j0) * Cdim + c;
#pragma unroll
    for (int jj = 0; jj < 8; ++jj)
        if (j0 + jj < NG) eb[jj * Cdim] = acc[jj];
}

// ---- Stage C: full-row dense narrow kernel.
// Block (512 thr) owns (b, 128 l). 8 iters of 16 l:
//   stage next 50x321 rows = contiguous 64KB -> LDS (glds w16, double buffer)
//   compute: thread = channel pair (161 active), f32x2 gather, pk FMA
//   store: 16x321 out-tile as one contiguous 20.5KB float4 burst (512 thr)
__global__ __launch_bounds__(512) void narrow_dense_kernel(
        const float* __restrict__ x, const float* __restrict__ w1,
        const float* __restrict__ e, float* __restrict__ out) {
    __shared__ float ws[K1n];
    __shared__ float xt[2][XTF];          // 2 x 64 KB
    __shared__ float4 ob4[OBF / 4];       // 20.5 KB, 16B aligned
    float* ob = (float*)ob4;

    const int tid = threadIdx.x;
    if (tid < K1n) ws[tid] = w1[tid];

    const int bid = xcd_swizzle(blockIdx.x, gridDim.x);
    const int g0 = bid & (NLG - 1);
    const int b = bid >> 5;

    const float* xb = x + (size_t)b * (Ldim * Cdim);
    const int l00 = g0 * LBLK;

    auto STAGE = [&](int buf, int it) {
        const int l0 = l00 + it * TLD;
        const int lbase = l0 - R1;
        float* dst = &xt[buf][0];
        if (lbase >= 0 && l0 + 34 <= Ldim - 1) {
            // contiguous 16384-float window (reads 334 floats past row 50: in-bounds, unused)
            const float* gsrc = xb + (size_t)lbase * Cdim;
#pragma unroll
            for (int k = 0; k < 8; ++k) {
                const int chunk = tid + k * 512;   // < 4096, wave-uniform trip count
                __builtin_amdgcn_global_load_lds(
                    (const __attribute__((address_space(1))) void*)(gsrc + chunk * 4),
                    (__attribute__((address_space(3))) void*)(dst + chunk * 4),
                    16, 0, 0);
            }
        } else {
#pragma unroll 1
            for (int i = tid; i < TRWD * Cdim; i += 512) {
                const int r = i / Cdim;
                const int c = i - r * Cdim;
                dst[i] = xb[(size_t)mirror_idx(lbase + r) * Cdim + c];
            }
        }
    };

    STAGE(0, 0);

    const int cpair = tid;              // pair id: c = 2*tid, 2*tid+1
    const bool active = (cpair <= 160); // 161 pair-threads cover 321 cols
    const int c2 = 2 * cpair;
    const int ylim = (cpair < 160) ? 1 : 0;   // pair 160: col 321 is phantom

#pragma unroll 1
    for (int it = 0; it < NITER; ++it) {
        __syncthreads();   // xt[it&1] staged; ob free (prev store's LDS reads done)

        if (it + 1 < NITER) STAGE((it & 1) ^ 1, it + 1);   // overlap with compute

        const int l0 = l00 + it * TLD;

        if (active) {
            const float* xcur = &xt[it & 1][0];
            f32x2 row[TRWD];
#pragma unroll
            for (int i = 0; i < TRWD; ++i) {
                const int a = i * Cdim + c2;
                row[i].x = xcur[a];
                row[i].y = xcur[a + 1];   // pair 160 reads next row col0: staged, unused
            }

            f32x2 acc[TLD];
#pragma unroll
            for (int m = 0; m < TLD; ++m) acc[m] = (f32x2)(0.f);
#pragma unroll
            for (int t = 0; t < K1n; ++t) {
                const float wt = ws[t];
                const f32x2 w2 = {wt, wt};
#pragma unroll
                for (int m = 0; m < TLD; ++m)
                    acc[m] = __builtin_elementwise_fma(w2, row[t + m], acc[m]);
            }

            // e interp: all 16 l's in coarse interval j0 = l0/16
            const int j0 = l0 >> 4;
            const float* eb = e + ((size_t)b * NG + j0) * Cdim + c2;
            const float z0x = eb[0],        z0y = eb[ylim];
            const float z1x = eb[Cdim],     z1y = eb[Cdim + ylim];
            const float dzx = (z1x - z0x) * 0.0625f;
            const float dzy = (z1y - z0y) * 0.0625f;

#pragma unroll
            for (int m = 0; m < TLD; ++m) {
                const int o = m * Cdim + c2;
                ob[o] = acc[m].x - fmaf(dzx, (float)m, z0x);
                if (cpair < 160)
                    ob[o + 1] = acc[m].y - fmaf(dzy, (float)m, z0y);
            }
        }

        __syncthreads();   // ob complete (also drains next-stage loads after compute)

        // dense contiguous store: 16 rows x 321 c = 1284 float4
        float4* og4 = (float4*)(out + ((size_t)b * Ldim + l0) * Cdim);
#pragma unroll
        for (int k = 0; k < 3; ++k) {
            const int idx = tid + k * 512;
            if (idx < OBF / 4) og4[idx] = ob4[idx];
        }
    }
}

// ---- reg-form narrow (middle-fallback path), proven round-3 structure
__global__ __launch_bounds__(256, 2) void narrow_reg_kernel(
        const float* __restrict__ x, const float* __restrict__ w1,
        const float* __restrict__ e, float* __restrict__ out) {
    __shared__ float ws[K1n];
    if (threadIdx.x < K1n) ws[threadIdx.x] = w1[threadIdx.x];
    __syncthreads();

    const int lb = xcd_swizzle(blockIdx.x, gridDim.x);
    const int lin = lb * 256 + threadIdx.x;
    const int c = lin % Cdim;
    const int rest = lin / Cdim;
    const int seg = rest % NSEG;
    const int b = rest / NSEG;
    if (b >= Bdim) return;

    const int l0 = seg * 32;
    const float* xb = x + b * (Ldim * Cdim) + c;

    const int j0 = seg * 2;
    const float* eb = e + (b * NG + j0) * Cdim + c;
    const float z0 = eb[0];
    const float z1 = eb[Cdim];
    const float z2 = eb[2 * Cdim];

    float row[66];
    if (seg >= 1 && seg <= 126) {
        const float* xp = xb + (l0 - R1) * Cdim;
#pragma unroll
        for (int i = 0; i < 66; ++i) row[i] = xp[i * Cdim];
    } else {
#pragma unroll
        for (int i = 0; i < 66; ++i)
            row[i] = xb[mirror_idx(l0 - R1 + i) * Cdim];
    }

    float acc[32];
#pragma unroll
    for (int m = 0; m < 32; ++m) acc[m] = 0.f;
#pragma unroll
    for (int t = 0; t < K1n; ++t) {
        const float wt = ws[t];
#pragma unroll
        for (int m = 0; m < 32; ++m)
            acc[m] = fmaf(wt, row[t + m], acc[m]);
    }

    const float d0 = (z1 - z0) * (1.0f / 16.0f);
    const float d1 = (z2 - z1) * (1.0f / 16.0f);
    float* ob = out + (b * Ldim + l0) * Cdim + c;
#pragma unroll
    for (int m = 0; m < 16; ++m)
        ob[m * Cdim] = acc[m] - fmaf(d0, (float)m, z0);
#pragma unroll
    for (int m = 16; m < 32; ++m)
        ob[m * Cdim] = acc[m] - fmaf(d1, (float)(m - 16), z1);
}

// ---- Middle fallback: direct 769-tap wide conv on the stride-16 grid
#define JPT 16
#define NJG 17
__global__ __launch_bounds__(256, 2) void wide_mid_kernel(
        const float* __restrict__ x, const float* __restrict__ w2p,
        float* __restrict__ z) {
    __shared__ float w2s[784];
    for (int i = threadIdx.x; i < 784; i += 256) w2s[i] = w2p[i];
    __syncthreads();

    const int gid = blockIdx.x * 256 + threadIdx.x;
    const int c = gid % Cdim;
    const int rest = gid / Cdim;
    const int jg = rest % NJG;
    const int b = rest / NJG;
    if (b >= Bdim) return;

    const int j0 = jg * JPT;
    const float* xb = x + b * (Ldim * Cdim) + c;

    float acc[JPT];
#pragma unroll
    for (int jj = 0; jj < JPT; ++jj) acc[jj] = 0.f;

    const bool interior = (j0 >= 24) && (16 * (j0 + 39) + 15 <= Ldim - 1);

#pragma unroll 1
    for (int p = 0; p < 16; ++p) {
        float row[64];
        if (interior) {
            const float* xp = xb + (16 * (j0 - 24) + p) * Cdim;
#pragma unroll
            for (int i = 0; i < 64; ++i) row[i] = xp[i * (16 * Cdim)];
        } else {
#pragma unroll
            for (int i = 0; i < 64; ++i)
                row[i] = xb[mirror_idx(16 * (j0 - 24 + i) + p) * Cdim];
        }
#pragma unroll
        for (int q = 0; q < 49; ++q) {
            const float wq = w2s[q * 16 + p];
#pragma unroll
            for (int jj = 0; jj < JPT; ++jj)
                acc[jj] = fmaf(wq, row[q + jj], acc[jj]);
        }
    }

    float* zb = z + (b * NG + j0) * Cdim + c;
#pragma unroll
    for (int jj = 0; jj < JPT; ++jj)
        if (j0 + jj < NG) zb[jj * Cdim] = acc[jj];
}

// ---- Last-resort fallback: fully direct
__global__ __launch_bounds__(256) void naive_kernel(
        const float* __restrict__ x, const float* __restrict__ w,
        float* __restrict__ out) {
    const int gid = blockIdx.x * 256 + threadIdx.x;
    if (gid >= Bdim * Ldim * Cdim) return;
    const int c = gid % Cdim;
    const int rest = gid / Cdim;
    const int l = rest % Ldim;
    const int b = rest / Ldim;
    const float* xb = x + b * (Ldim * Cdim) + c;
    float a2 = 0.f, a1 = 0.f;
    for (int t = 0; t < K2n; ++t)
        a2 = fmaf(w[K2_OFF + t], xb[mirror_idx(l + t - R2) * Cdim], a2);
#pragma unroll
    for (int t = 0; t < K1n; ++t)
        a1 = fmaf(w[W1_OFF + t], xb[mirror_idx(l + t - R1) * Cdim], a1);
    out[gid] = a1 - a2;
}

extern "C" void kernel_launch(void* const* d_in, const int* in_sizes, int n_in,
                              void* d_out, int out_size, void* d_ws, size_t ws_size,
                              hipStream_t stream) {
    (void)in_sizes; (void)n_in; (void)out_size;
    const float* x = (const float*)d_in[0];
    float* out = (float*)d_out;
    float* w = (float*)d_ws;

    hipLaunchKernelGGL(init_weights_kernel, dim3(1), dim3(1024), 0, stream, w);

    const size_t need_pyr = (size_t)WS_TOT * sizeof(float);
    const size_t need_mid = (size_t)(E2_OFF + Bdim * NG * Cdim) * sizeof(float);

    if (ws_size >= need_pyr) {
        const int a_total = Bdim * NGRP_A * Cdim;      // 205,440
        hipLaunchKernelGGL(decimA_kernel, dim3((a_total + 255) / 256), dim3(256),
                           0, stream, x, w + GA_OFF, w + D_OFF);
        const int b_total = Bdim * NTJ * Cdim;         // 338,976
        hipLaunchKernelGGL(coarseB_kernel, dim3((b_total + 255) / 256), dim3(256),
                           0, stream, w + D_OFF, w + GB_OFF, w + E_OFF);
        const int nblk = Bdim * NLG;                   // 1024 blocks
        hipLaunchKernelGGL(narrow_dense_kernel, dim3(nblk), dim3(512),
                           0, stream, x, w + W1_OFF, w + E_OFF, out);
    } else if (ws_size >= need_mid) {
        const int wide_total = Bdim * NJG * Cdim;
        hipLaunchKernelGGL(wide_mid_kernel, dim3((wide_total + 255) / 256), dim3(256),
                           0, stream, x, w + K2P_OFF, w + E2_OFF);
        const int nar_total = Bdim * NSEG * Cdim;
        hipLaunchKernelGGL(narrow_reg_kernel, dim3((nar_total + 255) / 256), dim3(256),
                           0, stream, x, w + W1_OFF, w + E2_OFF, out);
    } else {
        const int total = Bdim * Ldim * Cdim;
        hipLaunchKernelGGL(naive_kernel, dim3((total + 255) / 256), dim3(256),
                           0, stream, x, w, out);
    }
}

// Round 9
// 173.959 us; speedup vs baseline: 1.1960x; 1.1960x over previous
//
#include <hip/hip_runtime.h>
#include <math.h>

// DoG seasonal: out[b,l,c] = (k1*x)(l) - (k2*x)(l), depthwise over c, reflect pad.
// k1: sigma=4.2 (35 taps) exact. k2: sigma=96 (769 taps) via Gaussian pyramid:
//   A: d = (G12 * x) decimated by 16 (97 taps); B: e = gb * d (49 taps);
//   C (narrow): exact 35-tap conv + linear interp of e + subtract.
// R2: gather-form only (scatter -> scratch). R4: never cap VGPR below footprint.
// R5/R6: VALU not the wall. R7: intra-block pipelining null.
// R8: dense writes + 152KB LDS -> 1 block/CU -> serialization (152us); W untested.
// R9 (this): clean W-test. r3 reg-gather reads (proven 106us) + full-C blocks
//   (384 thr, 1 c/thread) + 20.5KB LDS out-tile + contiguous float4 burst store.
//   High occupancy, no input staging, only change vs r3 = dense stores.

#define Bdim 32
#define Ldim 4096
#define Cdim 321

#define R1 17
#define K1n 35
#define R2 384
#define K2n 769

#define GA_R 48
#define GA_N 97          // sigma_a = 12
#define GB_R 24
#define GB_N 49          // sigma_b = sqrt(96^2-12^2)/16 on coarse grid

#define NG 257           // e grid: j = 0..256 at l = 16j
#define NJD 305          // d grid: jj = -24..280 stored at jj+24
#define NGRP_A 20        // stage A: groups of 16 d-points
#define NTJ 33           // stage B: groups of 8 outputs

// narrow full-row tiling
#define TLF 16           // l per iteration
#define WINR 50          // TLF + 2*R1 window rows
#define NIT_F 4          // iters per block (64 l)
#define NLG2 64          // Ldim / 64
#define OBF4 1284        // 16*321/4 float4s in out-tile
#define NSEG 128         // reg-form fallback: segments of 32 outputs

// workspace float offsets
#define GA_OFF 0
#define GB_OFF 128
#define W1_OFF 192
#define K2_OFF 256       // 769 linear taps (naive fallback)
#define K2P_OFF 1088     // 784 polyphase-padded taps (middle fallback)
#define E2_OFF 4096      // middle-path e grid
#define D_OFF 4096       // pyramid d grid
#define E_OFF (D_OFF + Bdim*NJD*Cdim)            // 4096 + 3,132,960
#define WS_TOT (E_OFF + Bdim*NG*Cdim)            // + 2,639,904 floats

__device__ __forceinline__ int mirror_idx(int a) {
    a = a < 0 ? -a : a;
    a = a > (Ldim - 1) ? 2 * (Ldim - 1) - a : a;
    return a;
}

__device__ __forceinline__ int xcd_swizzle(int bid, int nwg) {
    // bijective XCD-chunk remap (m204)
    int q = nwg >> 3, r = nwg & 7;
    int xcd = bid & 7, i = bid >> 3;
    int base = (xcd < r) ? xcd * (q + 1) : r * (q + 1) + (xcd - r) * q;
    return base + i;
}

__device__ __forceinline__ float block_sum_1024(float v, float* partial) {
#pragma unroll
    for (int off = 32; off >= 1; off >>= 1) v += __shfl_down(v, off, 64);
    __syncthreads();
    if ((threadIdx.x & 63) == 0) partial[threadIdx.x >> 6] = v;
    __syncthreads();
    float s = partial[0];
#pragma unroll
    for (int i = 1; i < 16; ++i) s += partial[i];
    return s;
}

__global__ void init_weights_kernel(float* __restrict__ w) {
    __shared__ float partial[16];
    const int tid = threadIdx.x;  // 1024 threads

    {   // ga: sigma 12, radius 48
        float v = 0.f;
        if (tid < GA_N) { float t = (float)(tid - GA_R) * (1.0f / 12.0f); v = expf(-0.5f * t * t); }
        float s = block_sum_1024(v, partial);
        if (tid < GA_N) w[GA_OFF + tid] = v / s;
    }
    {   // gb
        const float sb = sqrtf(96.f * 96.f - 12.f * 12.f) * (1.0f / 16.0f);
        float v = 0.f;
        if (tid < GB_N) { float t = (float)(tid - GB_R) / sb; v = expf(-0.5f * t * t); }
        float s = block_sum_1024(v, partial);
        if (tid < GB_N) w[GB_OFF + tid] = v / s;
    }
    {   // w1: sigma 4.2
        float v = 0.f;
        if (tid < K1n) { float t = (float)(tid - R1) * (1.0f / 4.2f); v = expf(-0.5f * t * t); }
        float s = block_sum_1024(v, partial);
        if (tid < K1n) w[W1_OFF + tid] = v / s;
    }
    {   // k2: sigma 96 (fallbacks)
        float v = 0.f;
        if (tid < K2n) { float t = (float)(tid - R2) * (1.0f / 96.0f); v = expf(-0.5f * t * t); }
        float s = block_sum_1024(v, partial);
        if (tid < K2n) w[K2_OFF + tid] = v / s;
        if (tid < 784) w[K2P_OFF + tid] = (tid < K2n) ? v / s : 0.f;
    }
}

// ---- Stage A: d[b, jj+24, c], polyphase decimate-by-16 with G12 (97 taps)
__global__ __launch_bounds__(256) void decimA_kernel(
        const float* __restrict__ x, const float* __restrict__ ga,
        float* __restrict__ d) {
    __shared__ float gs[GA_N];
    if (threadIdx.x < GA_N) gs[threadIdx.x] = ga[threadIdx.x];
    __syncthreads();

    const int lb = xcd_swizzle(blockIdx.x, gridDim.x);
    const int lin = lb * 256 + threadIdx.x;
    const int c = lin % Cdim;
    const int rest = lin / Cdim;
    const int g = rest % NGRP_A;
    const int b = rest / NGRP_A;
    if (b >= Bdim) return;

    const int jj0 = -24 + 16 * g;
    const float* xb = x + b * (Ldim * Cdim) + c;

    float acc[16];
#pragma unroll
    for (int ii = 0; ii < 16; ++ii) acc[ii] = 0.f;

    const bool interior = (jj0 >= 3) && (jj0 <= 237);

#pragma unroll 1
    for (int p = 0; p < 16; ++p) {
        float row[22];
        if (interior) {
            const float* xp = xb + (16 * (jj0 - 3) + p) * Cdim;
#pragma unroll
            for (int i = 0; i < 22; ++i) row[i] = xp[i * (16 * Cdim)];
        } else {
#pragma unroll
            for (int i = 0; i < 22; ++i)
                row[i] = xb[mirror_idx(16 * (jj0 - 3 + i) + p) * Cdim];
        }
#pragma unroll
        for (int q = 0; q < 6; ++q) {
            const float wq = gs[16 * q + p];
#pragma unroll
            for (int ii = 0; ii < 16; ++ii)
                acc[ii] = fmaf(wq, row[ii + q], acc[ii]);
        }
        if (p == 0) {
            const float w6 = gs[96];
#pragma unroll
            for (int ii = 0; ii < 16; ++ii)
                acc[ii] = fmaf(w6, row[ii + 6], acc[ii]);
        }
    }

    const int j0d = jj0 + 24;
    float* db = d + (b * NJD + j0d) * Cdim + c;
#pragma unroll
    for (int ii = 0; ii < 16; ++ii)
        if (j0d + ii < NJD) db[ii * Cdim] = acc[ii];
}

// ---- Stage B: e = gb * d on coarse grid
__global__ __launch_bounds__(256) void coarseB_kernel(
        const float* __restrict__ d, const float* __restrict__ gb,
        float* __restrict__ e) {
    __shared__ float gbs[GB_N];
    if (threadIdx.x < GB_N) gbs[threadIdx.x] = gb[threadIdx.x];
    __syncthreads();

    const int lin = blockIdx.x * 256 + threadIdx.x;
    const int c = lin % Cdim;
    const int rest = lin / Cdim;
    const int tj = rest % NTJ;
    const int b = rest / NTJ;
    if (b >= Bdim) return;

    const int j0 = tj * 8;
    const float* db = d + b * (NJD * Cdim) + c;

    float row[56];
#pragma unroll
    for (int r = 0; r < 56; ++r) {
        int idx = j0 + r;
        idx = idx > (NJD - 1) ? (NJD - 1) : idx;
        row[r] = db[idx * Cdim];
    }

    float acc[8];
#pragma unroll
    for (int jj = 0; jj < 8; ++jj) acc[jj] = 0.f;
#pragma unroll
    for (int s = 0; s < GB_N; ++s) {
        const float wv = gbs[s];
#pragma unroll
        for (int jj = 0; jj < 8; ++jj)
            acc[jj] = fmaf(wv, row[s + jj], acc[jj]);
    }

    float* eb = e + (b * NG + j0) * Cdim + c;
#pragma unroll
    for (int jj = 0; jj < 8; ++jj)
        if (j0 + jj < NG) eb[jj * Cdim] = acc[jj];
}

// ---- Stage C: full-C narrow kernel, reg-gather reads + dense burst stores.
// Block (384 thr) = (b, 64 l). Thread = one channel c (321 active).
// Per 16-l iter: row[50] strided gather (r3-proven), 560 FMA, interp;
// out-tile in LDS (20.5 KB), then contiguous float4 burst by all 384 threads.
__global__ __launch_bounds__(384) void narrow_full_kernel(
        const float* __restrict__ x, const float* __restrict__ w1,
        const float* __restrict__ e, float* __restrict__ out) {
    __shared__ float ws[K1n];
    __shared__ float4 ob4[OBF4];          // 20544 B
    float* ob = (float*)ob4;

    const int tid = threadIdx.x;
    if (tid < K1n) ws[tid] = w1[tid];
    __syncthreads();

    const int bid = xcd_swizzle(blockIdx.x, gridDim.x);
    const int g0 = bid & (NLG2 - 1);
    const int b = bid >> 6;

    const int c = tid;
    const bool active = (c < Cdim);
    const float* xc = x + (size_t)b * (Ldim * Cdim) + c;   // column base

#pragma unroll 1
    for (int it = 0; it < NIT_F; ++it) {
        const int l0 = g0 * 64 + it * TLF;
        float res[TLF];

        if (active) {
            const int lbase = l0 - R1;
            float row[WINR];
            if (l0 >= 32 && l0 <= 4048) {
                const float* p = xc + (size_t)lbase * Cdim;
#pragma unroll
                for (int i = 0; i < WINR; ++i) row[i] = p[(size_t)i * Cdim];
            } else {
#pragma unroll
                for (int i = 0; i < WINR; ++i)
                    row[i] = xc[(size_t)mirror_idx(lbase + i) * Cdim];
            }

            float acc[TLF];
#pragma unroll
            for (int m = 0; m < TLF; ++m) acc[m] = 0.f;
#pragma unroll
            for (int t = 0; t < K1n; ++t) {
                const float wt = ws[t];
#pragma unroll
                for (int m = 0; m < TLF; ++m)
                    acc[m] = fmaf(wt, row[t + m], acc[m]);
            }

            // e interp: all 16 l's in coarse interval j = l0/16
            const int j = l0 >> 4;
            const float z0 = e[((size_t)b * NG + j) * Cdim + c];
            const float z1 = e[((size_t)b * NG + j + 1) * Cdim + c];
            const float dz = (z1 - z0) * 0.0625f;
#pragma unroll
            for (int m = 0; m < TLF; ++m)
                res[m] = acc[m] - fmaf(dz, (float)m, z0);
        }

        __syncthreads();   // previous burst finished reading ob
        if (active) {
#pragma unroll
            for (int m = 0; m < TLF; ++m) ob[m * Cdim + c] = res[m];
        }
        __syncthreads();   // ob complete

        float4* dst4 = (float4*)(out + ((size_t)b * Ldim + l0) * Cdim);
#pragma unroll
        for (int k = 0; k < 4; ++k) {
            const int idx = tid + k * 384;
            if (idx < OBF4) dst4[idx] = ob4[idx];
        }
    }
}

// ---- reg-form narrow (middle-fallback path), proven round-3 structure
__global__ __launch_bounds__(256, 2) void narrow_reg_kernel(
        const float* __restrict__ x, const float* __restrict__ w1,
        const float* __restrict__ e, float* __restrict__ out) {
    __shared__ float ws[K1n];
    if (threadIdx.x < K1n) ws[threadIdx.x] = w1[threadIdx.x];
    __syncthreads();

    const int lb = xcd_swizzle(blockIdx.x, gridDim.x);
    const int lin = lb * 256 + threadIdx.x;
    const int c = lin % Cdim;
    const int rest = lin / Cdim;
    const int seg = rest % NSEG;
    const int b = rest / NSEG;
    if (b >= Bdim) return;

    const int l0 = seg * 32;
    const float* xb = x + b * (Ldim * Cdim) + c;

    const int j0 = seg * 2;
    const float* eb = e + (b * NG + j0) * Cdim + c;
    const float z0 = eb[0];
    const float z1 = eb[Cdim];
    const float z2 = eb[2 * Cdim];

    float row[66];
    if (seg >= 1 && seg <= 126) {
        const float* xp = xb + (l0 - R1) * Cdim;
#pragma unroll
        for (int i = 0; i < 66; ++i) row[i] = xp[i * Cdim];
    } else {
#pragma unroll
        for (int i = 0; i < 66; ++i)
            row[i] = xb[mirror_idx(l0 - R1 + i) * Cdim];
    }

    float acc[32];
#pragma unroll
    for (int m = 0; m < 32; ++m) acc[m] = 0.f;
#pragma unroll
    for (int t = 0; t < K1n; ++t) {
        const float wt = ws[t];
#pragma unroll
        for (int m = 0; m < 32; ++m)
            acc[m] = fmaf(wt, row[t + m], acc[m]);
    }

    const float d0 = (z1 - z0) * (1.0f / 16.0f);
    const float d1 = (z2 - z1) * (1.0f / 16.0f);
    float* ob = out + (b * Ldim + l0) * Cdim + c;
#pragma unroll
    for (int m = 0; m < 16; ++m)
        ob[m * Cdim] = acc[m] - fmaf(d0, (float)m, z0);
#pragma unroll
    for (int m = 16; m < 32; ++m)
        ob[m * Cdim] = acc[m] - fmaf(d1, (float)(m - 16), z1);
}

// ---- Middle fallback: direct 769-tap wide conv on the stride-16 grid
#define JPT 16
#define NJG 17
__global__ __launch_bounds__(256, 2) void wide_mid_kernel(
        const float* __restrict__ x, const float* __restrict__ w2p,
        float* __restrict__ z) {
    __shared__ float w2s[784];
    for (int i = threadIdx.x; i < 784; i += 256) w2s[i] = w2p[i];
    __syncthreads();

    const int gid = blockIdx.x * 256 + threadIdx.x;
    const int c = gid % Cdim;
    const int rest = gid / Cdim;
    const int jg = rest % NJG;
    const int b = rest / NJG;
    if (b >= Bdim) return;

    const int j0 = jg * JPT;
    const float* xb = x + b * (Ldim * Cdim) + c;

    float acc[JPT];
#pragma unroll
    for (int jj = 0; jj < JPT; ++jj) acc[jj] = 0.f;

    const bool interior = (j0 >= 24) && (16 * (j0 + 39) + 15 <= Ldim - 1);

#pragma unroll 1
    for (int p = 0; p < 16; ++p) {
        float row[64];
        if (interior) {
            const float* xp = xb + (16 * (j0 - 24) + p) * Cdim;
#pragma unroll
            for (int i = 0; i < 64; ++i) row[i] = xp[i * (16 * Cdim)];
        } else {
#pragma unroll
            for (int i = 0; i < 64; ++i)
                row[i] = xb[mirror_idx(16 * (j0 - 24 + i) + p) * Cdim];
        }
#pragma unroll
        for (int q = 0; q < 49; ++q) {
            const float wq = w2s[q * 16 + p];
#pragma unroll
            for (int jj = 0; jj < JPT; ++jj)
                acc[jj] = fmaf(wq, row[q + jj], acc[jj]);
        }
    }

    float* zb = z + (b * NG + j0) * Cdim + c;
#pragma unroll
    for (int jj = 0; jj < JPT; ++jj)
        if (j0 + jj < NG) zb[jj * Cdim] = acc[jj];
}

// ---- Last-resort fallback: fully direct
__global__ __launch_bounds__(256) void naive_kernel(
        const float* __restrict__ x, const float* __restrict__ w,
        float* __restrict__ out) {
    const int gid = blockIdx.x * 256 + threadIdx.x;
    if (gid >= Bdim * Ldim * Cdim) return;
    const int c = gid % Cdim;
    const int rest = gid / Cdim;
    const int l = rest % Ldim;
    const int b = rest / Ldim;
    const float* xb = x + b * (Ldim * Cdim) + c;
    float a2 = 0.f, a1 = 0.f;
    for (int t = 0; t < K2n; ++t)
        a2 = fmaf(w[K2_OFF + t], xb[mirror_idx(l + t - R2) * Cdim], a2);
#pragma unroll
    for (int t = 0; t < K1n; ++t)
        a1 = fmaf(w[W1_OFF + t], xb[mirror_idx(l + t - R1) * Cdim], a1);
    out[gid] = a1 - a2;
}

extern "C" void kernel_launch(void* const* d_in, const int* in_sizes, int n_in,
                              void* d_out, int out_size, void* d_ws, size_t ws_size,
                              hipStream_t stream) {
    (void)in_sizes; (void)n_in; (void)out_size;
    const float* x = (const float*)d_in[0];
    float* out = (float*)d_out;
    float* w = (float*)d_ws;

    hipLaunchKernelGGL(init_weights_kernel, dim3(1), dim3(1024), 0, stream, w);

    const size_t need_pyr = (size_t)WS_TOT * sizeof(float);
    const size_t need_mid = (size_t)(E2_OFF + Bdim * NG * Cdim) * sizeof(float);

    if (ws_size >= need_pyr) {
        const int a_total = Bdim * NGRP_A * Cdim;      // 205,440
        hipLaunchKernelGGL(decimA_kernel, dim3((a_total + 255) / 256), dim3(256),
                           0, stream, x, w + GA_OFF, w + D_OFF);
        const int b_total = Bdim * NTJ * Cdim;         // 338,976
        hipLaunchKernelGGL(coarseB_kernel, dim3((b_total + 255) / 256), dim3(256),
                           0, stream, w + D_OFF, w + GB_OFF, w + E_OFF);
        const int nblk = Bdim * NLG2;                  // 2048 blocks
        hipLaunchKernelGGL(narrow_full_kernel, dim3(nblk), dim3(384),
                           0, stream, x, w + W1_OFF, w + E_OFF, out);
    } else if (ws_size >= need_mid) {
        const int wide_total = Bdim * NJG * Cdim;
        hipLaunchKernelGGL(wide_mid_kernel, dim3((wide_total + 255) / 256), dim3(256),
                           0, stream, x, w + K2P_OFF, w + E2_OFF);
        const int nar_total = Bdim * NSEG * Cdim;
        hipLaunchKernelGGL(narrow_reg_kernel, dim3((nar_total + 255) / 256), dim3(256),
                           0, stream, x, w + W1_OFF, w + E2_OFF, out);
    } else {
        const int total = Bdim * Ldim * Cdim;
        hipLaunchKernelGGL(naive_kernel, dim3((total + 255) / 256), dim3(256),
                           0, stream, x, w, out);
    }
}

// Round 10
// 161.617 us; speedup vs baseline: 1.2873x; 1.0764x over previous
//
#include <hip/hip_runtime.h>
#include <math.h>

// DoG seasonal: out[b,l,c] = (k1*x)(l) - (k2*x)(l), depthwise over c, reflect pad.
// k1: sigma=4.2 (35 taps) exact. k2: sigma=96 (769 taps) via Gaussian pyramid:
//   A: d = (G12 * x) decimated by 16 (97 taps); B: e = gb * d (49 taps);
//   C (narrow): exact 35-tap conv + linear interp of e + subtract.
// R2: gather-form only. R4: never cap VGPR below footprint. R5/R6: VALU not
// the wall. R7: pipelining null. R9: dense writes null (W dead); occupancy
// confound. R10: combine all levers: 32lx128c tiles (33.8KB LDS, 4 blk/CU),
// glds w16 2-rows-per-instr staging (1KB/instr, branchless per-lane mirror),
// ct innermost in XCD swizzle (page locality), pk-fma, no duplicate writes.

#define Bdim 32
#define Ldim 4096
#define Cdim 321

#define R1 17
#define K1n 35
#define R2 384
#define K2n 769

#define GA_R 48
#define GA_N 97          // sigma_a = 12
#define GB_R 24
#define GB_N 49          // sigma_b = sqrt(96^2-12^2)/16 on coarse grid

#define NG 257           // e grid: j = 0..256 at l = 16j
#define NJD 305          // d grid: jj = -24..280 stored at jj+24
#define NGRP_A 20        // stage A: groups of 16 d-points
#define NTJ 33           // stage B: groups of 8 outputs

// narrow v10 tiling
#define TLN 32           // l outputs per block
#define WR 66            // window rows = TLN + 2*R1
#define LSTR 128         // LDS row stride (floats)
#define NLG3 128         // Ldim / TLN
#define NCT3 3           // c tiles: widths 128,128,65
#define NSEG 128         // reg-form fallback: segments of 32 outputs

// workspace float offsets
#define GA_OFF 0
#define GB_OFF 128
#define W1_OFF 192
#define K2_OFF 256       // 769 linear taps (naive fallback)
#define K2P_OFF 1088     // 784 polyphase-padded taps (middle fallback)
#define E2_OFF 4096      // middle-path e grid
#define D_OFF 4096       // pyramid d grid
#define E_OFF (D_OFF + Bdim*NJD*Cdim)            // 4096 + 3,132,960
#define WS_TOT (E_OFF + Bdim*NG*Cdim)            // + 2,639,904 floats

typedef float f32x2 __attribute__((ext_vector_type(2)));

__device__ __forceinline__ int mirror_idx(int a) {
    a = a < 0 ? -a : a;
    a = a > (Ldim - 1) ? 2 * (Ldim - 1) - a : a;
    return a;
}

__device__ __forceinline__ int xcd_swizzle(int bid, int nwg) {
    // bijective XCD-chunk remap (m204)
    int q = nwg >> 3, r = nwg & 7;
    int xcd = bid & 7, i = bid >> 3;
    int base = (xcd < r) ? xcd * (q + 1) : r * (q + 1) + (xcd - r) * q;
    return base + i;
}

__device__ __forceinline__ float block_sum_1024(float v, float* partial) {
#pragma unroll
    for (int off = 32; off >= 1; off >>= 1) v += __shfl_down(v, off, 64);
    __syncthreads();
    if ((threadIdx.x & 63) == 0) partial[threadIdx.x >> 6] = v;
    __syncthreads();
    float s = partial[0];
#pragma unroll
    for (int i = 1; i < 16; ++i) s += partial[i];
    return s;
}

__global__ void init_weights_kernel(float* __restrict__ w) {
    __shared__ float partial[16];
    const int tid = threadIdx.x;  // 1024 threads

    {   // ga: sigma 12, radius 48
        float v = 0.f;
        if (tid < GA_N) { float t = (float)(tid - GA_R) * (1.0f / 12.0f); v = expf(-0.5f * t * t); }
        float s = block_sum_1024(v, partial);
        if (tid < GA_N) w[GA_OFF + tid] = v / s;
    }
    {   // gb
        const float sb = sqrtf(96.f * 96.f - 12.f * 12.f) * (1.0f / 16.0f);
        float v = 0.f;
        if (tid < GB_N) { float t = (float)(tid - GB_R) / sb; v = expf(-0.5f * t * t); }
        float s = block_sum_1024(v, partial);
        if (tid < GB_N) w[GB_OFF + tid] = v / s;
    }
    {   // w1: sigma 4.2
        float v = 0.f;
        if (tid < K1n) { float t = (float)(tid - R1) * (1.0f / 4.2f); v = expf(-0.5f * t * t); }
        float s = block_sum_1024(v, partial);
        if (tid < K1n) w[W1_OFF + tid] = v / s;
    }
    {   // k2: sigma 96 (fallbacks)
        float v = 0.f;
        if (tid < K2n) { float t = (float)(tid - R2) * (1.0f / 96.0f); v = expf(-0.5f * t * t); }
        float s = block_sum_1024(v, partial);
        if (tid < K2n) w[K2_OFF + tid] = v / s;
        if (tid < 784) w[K2P_OFF + tid] = (tid < K2n) ? v / s : 0.f;
    }
}

// ---- Stage A: d[b, jj+24, c], polyphase decimate-by-16 with G12 (97 taps)
__global__ __launch_bounds__(256) void decimA_kernel(
        const float* __restrict__ x, const float* __restrict__ ga,
        float* __restrict__ d) {
    __shared__ float gs[GA_N];
    if (threadIdx.x < GA_N) gs[threadIdx.x] = ga[threadIdx.x];
    __syncthreads();

    const int lb = xcd_swizzle(blockIdx.x, gridDim.x);
    const int lin = lb * 256 + threadIdx.x;
    const int c = lin % Cdim;
    const int rest = lin / Cdim;
    const int g = rest % NGRP_A;
    const int b = rest / NGRP_A;
    if (b >= Bdim) return;

    const int jj0 = -24 + 16 * g;
    const float* xb = x + b * (Ldim * Cdim) + c;

    float acc[16];
#pragma unroll
    for (int ii = 0; ii < 16; ++ii) acc[ii] = 0.f;

    const bool interior = (jj0 >= 3) && (jj0 <= 237);

#pragma unroll 1
    for (int p = 0; p < 16; ++p) {
        float row[22];
        if (interior) {
            const float* xp = xb + (16 * (jj0 - 3) + p) * Cdim;
#pragma unroll
            for (int i = 0; i < 22; ++i) row[i] = xp[i * (16 * Cdim)];
        } else {
#pragma unroll
            for (int i = 0; i < 22; ++i)
                row[i] = xb[mirror_idx(16 * (jj0 - 3 + i) + p) * Cdim];
        }
#pragma unroll
        for (int q = 0; q < 6; ++q) {
            const float wq = gs[16 * q + p];
#pragma unroll
            for (int ii = 0; ii < 16; ++ii)
                acc[ii] = fmaf(wq, row[ii + q], acc[ii]);
        }
        if (p == 0) {
            const float w6 = gs[96];
#pragma unroll
            for (int ii = 0; ii < 16; ++ii)
                acc[ii] = fmaf(w6, row[ii + 6], acc[ii]);
        }
    }

    const int j0d = jj0 + 24;
    float* db = d + (b * NJD + j0d) * Cdim + c;
#pragma unroll
    for (int ii = 0; ii < 16; ++ii)
        if (j0d + ii < NJD) db[ii * Cdim] = acc[ii];
}

// ---- Stage B: e = gb * d on coarse grid
__global__ __launch_bounds__(256) void coarseB_kernel(
        const float* __restrict__ d, const float* __restrict__ gb,
        float* __restrict__ e) {
    __shared__ float gbs[GB_N];
    if (threadIdx.x < GB_N) gbs[threadIdx.x] = gb[threadIdx.x];
    __syncthreads();

    const int lin = blockIdx.x * 256 + threadIdx.x;
    const int c = lin % Cdim;
    const int rest = lin / Cdim;
    const int tj = rest % NTJ;
    const int b = rest / NTJ;
    if (b >= Bdim) return;

    const int j0 = tj * 8;
    const float* db = d + b * (NJD * Cdim) + c;

    float row[56];
#pragma unroll
    for (int r = 0; r < 56; ++r) {
        int idx = j0 + r;
        idx = idx > (NJD - 1) ? (NJD - 1) : idx;
        row[r] = db[idx * Cdim];
    }

    float acc[8];
#pragma unroll
    for (int jj = 0; jj < 8; ++jj) acc[jj] = 0.f;
#pragma unroll
    for (int s = 0; s < GB_N; ++s) {
        const float wv = gbs[s];
#pragma unroll
        for (int jj = 0; jj < 8; ++jj)
            acc[jj] = fmaf(wv, row[s + jj], acc[jj]);
    }

    float* eb = e + (b * NG + j0) * Cdim + c;
#pragma unroll
    for (int jj = 0; jj < 8; ++jj)
        if (j0 + jj < NG) eb[jj * Cdim] = acc[jj];
}

// ---- Stage C v10: 32l x 128c tiles, glds-w16 2-row staging, pk-fma, direct stores.
__global__ __launch_bounds__(256) void narrow_v10_kernel(
        const float* __restrict__ x, const float* __restrict__ w1,
        const float* __restrict__ e, float* __restrict__ out) {
    __shared__ float ws[K1n];
    __shared__ float tile[WR * LSTR];     // 33792 B
    if (threadIdx.x < K1n) ws[threadIdx.x] = w1[threadIdx.x];

    const int bid = xcd_swizzle(blockIdx.x, gridDim.x);
    // bid = (b*NLG3 + lg)*3 + ct ; ct innermost -> same rows' c-tiles adjacent
    const int ct = bid % NCT3;
    const int rest = bid / NCT3;
    const int lg = rest % NLG3;
    const int b = rest / NLG3;

    const int c0 = ct * 128;
    const int l0 = lg * TLN;
    const int lbase = l0 - R1;
    const int lane = threadIdx.x & 63;
    const int wv = threadIdx.x >> 6;
    const float* xb = x + (size_t)b * (Ldim * Cdim);

    if (ct < 2) {
        // stage 66 rows x 128c: 33 glds-w16 instrs, 2 rows per instr.
        // lane<32 -> row 2p, cols 4*lane ; lane>=32 -> row 2p+1, cols 4*(lane-32)
        const int rsel = (lane >> 5);          // 0 or 1
        const int coff = (lane & 31) * 4;
#pragma unroll
        for (int k = 0; k < 9; ++k) {
            const int p = wv + 4 * k;          // pair index, wave-uniform
            if (p < 33) {
                const int grow = mirror_idx(lbase + 2 * p + rsel);
                const float* g = xb + (size_t)grow * Cdim + c0 + coff;
                __builtin_amdgcn_global_load_lds(
                    (const __attribute__((address_space(1))) void*)g,
                    (__attribute__((address_space(3))) void*)(&tile[2 * p * LSTR]),
                    16, 0, 0);
            }
        }
    } else {
        // last tile: 65 cols (c 256..320), plain load + ds_write
#pragma unroll 1
        for (int i = threadIdx.x; i < WR * 65; i += 256) {
            const int r = i / 65;
            const int cc = i - r * 65;
            tile[r * LSTR + cc] = xb[(size_t)mirror_idx(lbase + r) * Cdim + 256 + cc];
        }
    }
    __syncthreads();

    // compute: thread = (cpair, lgrp): c = c0 + 2*cp (+1), l = l0 + lgrp*8 + m
    const int cp = threadIdx.x & 63;
    const int lgrp = threadIdx.x >> 6;
    const int lg8 = lgrp * 8;
    const int j = (l0 >> 4) + (lgrp >> 1);
    const float f0 = (float)((lgrp & 1) * 8);

    if (ct < 2 || cp < 32) {
        f32x2 r2[42];
#pragma unroll
        for (int i = 0; i < 42; ++i)
            r2[i] = *reinterpret_cast<const f32x2*>(&tile[(lg8 + i) * LSTR + 2 * cp]);

        f32x2 acc[8];
#pragma unroll
        for (int m = 0; m < 8; ++m) acc[m] = (f32x2)(0.f);
#pragma unroll
        for (int t = 0; t < K1n; ++t) {
            const float wt = ws[t];
            const f32x2 w2 = {wt, wt};
#pragma unroll
            for (int m = 0; m < 8; ++m)
                acc[m] = __builtin_elementwise_fma(w2, r2[t + m], acc[m]);
        }

        const int ce = c0 + 2 * cp;
        const float* eb = e + ((size_t)b * NG + j) * Cdim + ce;
        const float z0x = eb[0],    z0y = eb[1];
        const float z1x = eb[Cdim], z1y = eb[Cdim + 1];
        const float dzx = (z1x - z0x) * 0.0625f;
        const float dzy = (z1y - z0y) * 0.0625f;

        float* ob = out + ((size_t)b * Ldim + l0 + lg8) * Cdim + ce;
#pragma unroll
        for (int m = 0; m < 8; ++m) {
            const float fm = f0 + (float)m;
            ob[m * Cdim]     = acc[m].x - fmaf(dzx, fm, z0x);
            ob[m * Cdim + 1] = acc[m].y - fmaf(dzy, fm, z0y);
        }
    } else if (cp == 32) {
        // ct==2, column c=320 scalar path (tile col 64)
        float rs[42];
#pragma unroll
        for (int i = 0; i < 42; ++i) rs[i] = tile[(lg8 + i) * LSTR + 64];
        float acc[8];
#pragma unroll
        for (int m = 0; m < 8; ++m) acc[m] = 0.f;
#pragma unroll
        for (int t = 0; t < K1n; ++t) {
            const float wt = ws[t];
#pragma unroll
            for (int m = 0; m < 8; ++m)
                acc[m] = fmaf(wt, rs[t + m], acc[m]);
        }
        const float z0 = e[((size_t)b * NG + j) * Cdim + 320];
        const float z1 = e[((size_t)b * NG + j + 1) * Cdim + 320];
        const float dz = (z1 - z0) * 0.0625f;
        float* ob = out + ((size_t)b * Ldim + l0 + lg8) * Cdim + 320;
#pragma unroll
        for (int m = 0; m < 8; ++m)
            ob[m * Cdim] = acc[m] - fmaf(dz, f0 + (float)m, z0);
    }
}

// ---- reg-form narrow (middle-fallback path), proven round-3 structure
__global__ __launch_bounds__(256, 2) void narrow_reg_kernel(
        const float* __restrict__ x, const float* __restrict__ w1,
        const float* __restrict__ e, float* __restrict__ out) {
    __shared__ float ws[K1n];
    if (threadIdx.x < K1n) ws[threadIdx.x] = w1[threadIdx.x];
    __syncthreads();

    const int lb = xcd_swizzle(blockIdx.x, gridDim.x);
    const int lin = lb * 256 + threadIdx.x;
    const int c = lin % Cdim;
    const int rest = lin / Cdim;
    const int seg = rest % NSEG;
    const int b = rest / NSEG;
    if (b >= Bdim) return;

    const int l0 = seg * 32;
    const float* xb = x + b * (Ldim * Cdim) + c;

    const int j0 = seg * 2;
    const float* eb = e + (b * NG + j0) * Cdim + c;
    const float z0 = eb[0];
    const float z1 = eb[Cdim];
    const float z2 = eb[2 * Cdim];

    float row[66];
    if (seg >= 1 && seg <= 126) {
        const float* xp = xb + (l0 - R1) * Cdim;
#pragma unroll
        for (int i = 0; i < 66; ++i) row[i] = xp[i * Cdim];
    } else {
#pragma unroll
        for (int i = 0; i < 66; ++i)
            row[i] = xb[mirror_idx(l0 - R1 + i) * Cdim];
    }

    float acc[32];
#pragma unroll
    for (int m = 0; m < 32; ++m) acc[m] = 0.f;
#pragma unroll
    for (int t = 0; t < K1n; ++t) {
        const float wt = ws[t];
#pragma unroll
        for (int m = 0; m < 32; ++m)
            acc[m] = fmaf(wt, row[t + m], acc[m]);
    }

    const float d0 = (z1 - z0) * (1.0f / 16.0f);
    const float d1 = (z2 - z1) * (1.0f / 16.0f);
    float* ob = out + (b * Ldim + l0) * Cdim + c;
#pragma unroll
    for (int m = 0; m < 16; ++m)
        ob[m * Cdim] = acc[m] - fmaf(d0, (float)m, z0);
#pragma unroll
    for (int m = 16; m < 32; ++m)
        ob[m * Cdim] = acc[m] - fmaf(d1, (float)(m - 16), z1);
}

// ---- Middle fallback: direct 769-tap wide conv on the stride-16 grid
#define JPT 16
#define NJG 17
__global__ __launch_bounds__(256, 2) void wide_mid_kernel(
        const float* __restrict__ x, const float* __restrict__ w2p,
        float* __restrict__ z) {
    __shared__ float w2s[784];
    for (int i = threadIdx.x; i < 784; i += 256) w2s[i] = w2p[i];
    __syncthreads();

    const int gid = blockIdx.x * 256 + threadIdx.x;
    const int c = gid % Cdim;
    const int rest = gid / Cdim;
    const int jg = rest % NJG;
    const int b = rest / NJG;
    if (b >= Bdim) return;

    const int j0 = jg * JPT;
    const float* xb = x + b * (Ldim * Cdim) + c;

    float acc[JPT];
#pragma unroll
    for (int jj = 0; jj < JPT; ++jj) acc[jj] = 0.f;

    const bool interior = (j0 >= 24) && (16 * (j0 + 39) + 15 <= Ldim - 1);

#pragma unroll 1
    for (int p = 0; p < 16; ++p) {
        float row[64];
        if (interior) {
            const float* xp = xb + (16 * (j0 - 24) + p) * Cdim;
#pragma unroll
            for (int i = 0; i < 64; ++i) row[i] = xp[i * (16 * Cdim)];
        } else {
#pragma unroll
            for (int i = 0; i < 64; ++i)
                row[i] = xb[mirror_idx(16 * (j0 - 24 + i) + p) * Cdim];
        }
#pragma unroll
        for (int q = 0; q < 49; ++q) {
            const float wq = w2s[q * 16 + p];
#pragma unroll
            for (int jj = 0; jj < JPT; ++jj)
                acc[jj] = fmaf(wq, row[q + jj], acc[jj]);
        }
    }

    float* zb = z + (b * NG + j0) * Cdim + c;
#pragma unroll
    for (int jj = 0; jj < JPT; ++jj)
        if (j0 + jj < NG) zb[jj * Cdim] = acc[jj];
}

// ---- Last-resort fallback: fully direct
__global__ __launch_bounds__(256) void naive_kernel(
        const float* __restrict__ x, const float* __restrict__ w,
        float* __restrict__ out) {
    const int gid = blockIdx.x * 256 + threadIdx.x;
    if (gid >= Bdim * Ldim * Cdim) return;
    const int c = gid % Cdim;
    const int rest = gid / Cdim;
    const int l = rest % Ldim;
    const int b = rest / Ldim;
    const float* xb = x + b * (Ldim * Cdim) + c;
    float a2 = 0.f, a1 = 0.f;
    for (int t = 0; t < K2n; ++t)
        a2 = fmaf(w[K2_OFF + t], xb[mirror_idx(l + t - R2) * Cdim], a2);
#pragma unroll
    for (int t = 0; t < K1n; ++t)
        a1 = fmaf(w[W1_OFF + t], xb[mirror_idx(l + t - R1) * Cdim], a1);
    out[gid] = a1 - a2;
}

extern "C" void kernel_launch(void* const* d_in, const int* in_sizes, int n_in,
                              void* d_out, int out_size, void* d_ws, size_t ws_size,
                              hipStream_t stream) {
    (void)in_sizes; (void)n_in; (void)out_size;
    const float* x = (const float*)d_in[0];
    float* out = (float*)d_out;
    float* w = (float*)d_ws;

    hipLaunchKernelGGL(init_weights_kernel, dim3(1), dim3(1024), 0, stream, w);

    const size_t need_pyr = (size_t)WS_TOT * sizeof(float);
    const size_t need_mid = (size_t)(E2_OFF + Bdim * NG * Cdim) * sizeof(float);

    if (ws_size >= need_pyr) {
        const int a_total = Bdim * NGRP_A * Cdim;      // 205,440
        hipLaunchKernelGGL(decimA_kernel, dim3((a_total + 255) / 256), dim3(256),
                           0, stream, x, w + GA_OFF, w + D_OFF);
        const int b_total = Bdim * NTJ * Cdim;         // 338,976
        hipLaunchKernelGGL(coarseB_kernel, dim3((b_total + 255) / 256), dim3(256),
                           0, stream, w + D_OFF, w + GB_OFF, w + E_OFF);
        const int nblk = Bdim * NLG3 * NCT3;           // 12,288 blocks
        hipLaunchKernelGGL(narrow_v10_kernel, dim3(nblk), dim3(256),
                           0, stream, x, w + W1_OFF, w + E_OFF, out);
    } else if (ws_size >= need_mid) {
        const int wide_total = Bdim * NJG * Cdim;
        hipLaunchKernelGGL(wide_mid_kernel, dim3((wide_total + 255) / 256), dim3(256),
                           0, stream, x, w + K2P_OFF, w + E2_OFF);
        const int nar_total = Bdim * NSEG * Cdim;
        hipLaunchKernelGGL(narrow_reg_kernel, dim3((nar_total + 255) / 256), dim3(256),
                           0, stream, x, w + W1_OFF, w + E2_OFF, out);
    } else {
        const int total = Bdim * Ldim * Cdim;
        hipLaunchKernelGGL(naive_kernel, dim3((total + 255) / 256), dim3(256),
                           0, stream, x, w, out);
    }
}